// Round 3
// baseline (97.239 us; speedup 1.0000x reference)
//
#include <hip/hip_runtime.h>
#include <math.h>

#define THREADS 256
#define BLOCKS  2048
#define STRIDE  (BLOCKS * THREADS)

__device__ __forceinline__ float wave_reduce(float v) {
    #pragma unroll
    for (int off = 32; off > 0; off >>= 1)
        v += __shfl_down(v, off, 64);
    return v;
}

__device__ __forceinline__ void accum_elem(float pp, float pt, float md, float tg,
                                           float V, float& phys, float& lm) {
    constexpr float P_ATM    = 0.101325f;
    constexpr float BETA     = 1466.96f;
    constexpr float INV_BETA = 1.0f / 1466.96f;
    constexpr float R_FRAC   = 0.005f / 0.995f;
    constexpr float C_RP     = R_FRAC * P_ATM;
    constexpr float RHO_MIX  = 851.6f + 1.225f * R_FRAC;
    constexpr float PT_EPS   = 1e-12f;

    float p_used  = fmaxf(pp * 0.1f, 1.0f);
    float inv_pu  = __builtin_amdgcn_rcpf(p_used);
    float p_denom = C_RP * inv_pu;
    float p_ratio = p_denom * inv_pu;
    float e       = __expf((P_ATM - p_used) * INV_BETA) * INV_BETA;
    float denom   = BETA * e + p_denom;
    float inv_d   = __builtin_amdgcn_rcpf(denom);
    float drho    = RHO_MIX * (e + p_ratio) * inv_d * inv_d;

    float res  = V * drho * pt - md;
    bool  m    = fabsf(pt) >= PT_EPS;
    phys += m ? fabsf(res)     : 0.0f;
    lm   += m ? fabsf(tg - pp) : 0.0f;
}

// Fused: streaming partial reduction + ticket-based last-block finish.
__global__ __launch_bounds__(THREADS) void loss_fused_kernel(
    const float4* __restrict__ pp4,
    const float4* __restrict__ pt4,
    const float4* __restrict__ md4,
    const float4* __restrict__ tg4,
    const float*  __restrict__ Vp,
    const float*  __restrict__ logit,   // fault_logit (B,)
    const float*  __restrict__ yf,      // targets_fault (B,)
    int nb,
    unsigned*     __restrict__ counter, // zeroed via hipMemsetAsync each call
    float2*       __restrict__ partials,
    float*        __restrict__ out,
    int n4, float inv_ns)
{
    const float V = Vp[0];
    float phys = 0.0f;
    float lm   = 0.0f;

    const int tid = blockIdx.x * THREADS + threadIdx.x;

    // R1-style simple grid-stride loop (best measured variant).
    for (int i = tid; i < n4; i += STRIDE) {
        float4 a = pp4[i];
        float4 b = pt4[i];
        float4 c = md4[i];
        float4 d = tg4[i];
        const float* pa = (const float*)&a;
        const float* pb = (const float*)&b;
        const float* pc = (const float*)&c;
        const float* pd = (const float*)&d;
        #pragma unroll
        for (int j = 0; j < 4; ++j)
            accum_elem(pa[j], pb[j], pc[j], pd[j], V, phys, lm);
    }

    phys = wave_reduce(phys);
    lm   = wave_reduce(lm);

    __shared__ float sp[4];
    __shared__ float sl[4];
    __shared__ int   s_last;
    int lane = threadIdx.x & 63;
    int w    = threadIdx.x >> 6;
    if (lane == 0) { sp[w] = phys; sl[w] = lm; }
    __syncthreads();
    if (threadIdx.x == 0) {
        float P = sp[0] + sp[1] + sp[2] + sp[3];
        float L = sl[0] + sl[1] + sl[2] + sl[3];
        partials[blockIdx.x] = make_float2(P, L);
        __threadfence();                       // release: partial visible device-wide
        unsigned old = atomicAdd(counter, 1u); // device-scope
        s_last = (old == (unsigned)(gridDim.x - 1)) ? 1 : 0;
    }
    __syncthreads();
    if (!s_last) return;

    // ---- last block: final reduce + BCE + compose ----
    __threadfence();                           // acquire: see all partials

    float tp = 0.0f, tl = 0.0f, cls = 0.0f;
    for (int i = threadIdx.x; i < BLOCKS; i += THREADS) {
        float2 p = partials[i];
        tp += p.x;
        tl += p.y;
    }
    for (int i = threadIdx.x; i < nb; i += THREADS) {
        float x = logit[i];
        float y = yf[i];
        cls += fmaxf(x, 0.0f) - x * y + log1pf(__expf(-fabsf(x)));
    }

    tp  = wave_reduce(tp);
    tl  = wave_reduce(tl);
    cls = wave_reduce(cls);

    __shared__ float fp[4], fl[4], fc[4];
    __syncthreads();     // protect reuse ordering vs earlier shared writes
    if (lane == 0) { fp[w] = tp; fl[w] = tl; fc[w] = cls; }
    __syncthreads();
    if (threadIdx.x == 0) {
        float P = fp[0] + fp[1] + fp[2] + fp[3];
        float L = fl[0] + fl[1] + fl[2] + fl[3];
        float C = fc[0] + fc[1] + fc[2] + fc[3];

        float loss_physics = P * inv_ns;
        float loss_M       = L * inv_ns;
        float loss_cls     = C / (float)nb;

        out[0] = loss_M + 0.5f * loss_physics + 0.5f * loss_cls;
        out[1] = loss_M;
        out[2] = loss_physics;
        out[3] = loss_cls;
    }
}

extern "C" void kernel_launch(void* const* d_in, const int* in_sizes, int n_in,
                              void* d_out, int out_size, void* d_ws, size_t ws_size,
                              hipStream_t stream) {
    const float* p_pred   = (const float*)d_in[0];
    const float* p_t_pred = (const float*)d_in[1];
    const float* logit    = (const float*)d_in[2];
    const float* yfault   = (const float*)d_in[3];
    const float* mdot_A   = (const float*)d_in[4];
    const float* tgt_p    = (const float*)d_in[5];
    const float* V        = (const float*)d_in[6];

    int n  = in_sizes[0];       // B*S = 8388608
    int nb = in_sizes[3];       // B = 512
    int n4 = n / 4;

    // ws layout: [0..3] ticket counter, [256..] partials (BLOCKS float2)
    unsigned* counter  = (unsigned*)d_ws;
    float2*   partials = (float2*)((char*)d_ws + 256);

    hipMemsetAsync(counter, 0, sizeof(unsigned), stream);

    loss_fused_kernel<<<BLOCKS, THREADS, 0, stream>>>(
        (const float4*)p_pred, (const float4*)p_t_pred,
        (const float4*)mdot_A, (const float4*)tgt_p,
        V, logit, yfault, nb,
        counter, partials,
        (float*)d_out, n4, 1.0f / (float)n);
}

// Round 4
// 51.239 us; speedup vs baseline: 1.8978x; 1.8978x over previous
//
#include <hip/hip_runtime.h>
#include <math.h>

#define THREADS 256
#define BLOCKS  2048
#define STRIDE  (BLOCKS * THREADS)

__device__ __forceinline__ float wave_reduce(float v) {
    #pragma unroll
    for (int off = 32; off > 0; off >>= 1)
        v += __shfl_down(v, off, 64);
    return v;
}

__device__ __forceinline__ void accum_elem(float pp, float pt, float md, float tg,
                                           float V, float& phys, float& lm) {
    constexpr float P_ATM    = 0.101325f;
    constexpr float BETA     = 1466.96f;
    constexpr float INV_BETA = 1.0f / 1466.96f;
    constexpr float R_FRAC   = 0.005f / 0.995f;
    constexpr float C_RP     = R_FRAC * P_ATM;
    constexpr float RHO_MIX  = 851.6f + 1.225f * R_FRAC;
    constexpr float PT_EPS   = 1e-12f;

    float p_used  = fmaxf(pp * 0.1f, 1.0f);
    float inv_pu  = __builtin_amdgcn_rcpf(p_used);
    float p_denom = C_RP * inv_pu;
    float p_ratio = p_denom * inv_pu;
    float e       = __expf((P_ATM - p_used) * INV_BETA) * INV_BETA;
    float denom   = BETA * e + p_denom;
    float inv_d   = __builtin_amdgcn_rcpf(denom);
    float drho    = RHO_MIX * (e + p_ratio) * inv_d * inv_d;

    float res  = V * drho * pt - md;
    bool  m    = fabsf(pt) >= PT_EPS;
    phys += m ? fabsf(res)     : 0.0f;
    lm   += m ? fabsf(tg - pp) : 0.0f;
}

// Coherent (agent-scope, relaxed) helpers — write-through / cache-bypassing,
// NO buffer_wbl2 L2 flush (the R3 __threadfence pathology).
__device__ __forceinline__ void coh_store(float* p, float v) {
    __hip_atomic_store((unsigned*)p, __float_as_uint(v),
                       __ATOMIC_RELAXED, __HIP_MEMORY_SCOPE_AGENT);
}
__device__ __forceinline__ float coh_load(const float* p) {
    unsigned u = __hip_atomic_load((const unsigned*)p,
                                   __ATOMIC_RELAXED, __HIP_MEMORY_SCOPE_AGENT);
    return __uint_as_float(u);
}

// Fused: streaming partial reduction + hand-rolled last-block finish.
__global__ __launch_bounds__(THREADS) void loss_fused_kernel(
    const float4* __restrict__ pp4,
    const float4* __restrict__ pt4,
    const float4* __restrict__ md4,
    const float4* __restrict__ tg4,
    const float*  __restrict__ Vp,
    const float*  __restrict__ logit,
    const float*  __restrict__ yf,
    int nb,
    unsigned*     __restrict__ counter,  // zeroed via hipMemsetAsync each call
    float*        __restrict__ partials, // 2 floats per block
    float*        __restrict__ out,
    int n4, float inv_ns)
{
    const float V = Vp[0];
    float phys = 0.0f;
    float lm   = 0.0f;

    const int tid = blockIdx.x * THREADS + threadIdx.x;

    for (int i = tid; i < n4; i += STRIDE) {
        float4 a = pp4[i];
        float4 b = pt4[i];
        float4 c = md4[i];
        float4 d = tg4[i];
        const float* pa = (const float*)&a;
        const float* pb = (const float*)&b;
        const float* pc = (const float*)&c;
        const float* pd = (const float*)&d;
        #pragma unroll
        for (int j = 0; j < 4; ++j)
            accum_elem(pa[j], pb[j], pc[j], pd[j], V, phys, lm);
    }

    phys = wave_reduce(phys);
    lm   = wave_reduce(lm);

    __shared__ float sp[4];
    __shared__ float sl[4];
    __shared__ int   s_last;
    int lane = threadIdx.x & 63;
    int w    = threadIdx.x >> 6;
    if (lane == 0) { sp[w] = phys; sl[w] = lm; }
    __syncthreads();
    if (threadIdx.x == 0) {
        float P = sp[0] + sp[1] + sp[2] + sp[3];
        float L = sl[0] + sl[1] + sl[2] + sl[3];
        // coherent write-through stores (no L2 flush)
        coh_store(&partials[2 * blockIdx.x + 0], P);
        coh_store(&partials[2 * blockIdx.x + 1], L);
        // drain the stores to the coherence point, then take a ticket
        asm volatile("s_waitcnt vmcnt(0)" ::: "memory");
        unsigned old = __hip_atomic_fetch_add(counter, 1u,
                                              __ATOMIC_RELAXED,
                                              __HIP_MEMORY_SCOPE_AGENT);
        s_last = (old == (unsigned)(BLOCKS - 1)) ? 1 : 0;
    }
    __syncthreads();
    if (!s_last) return;

    // ---- last block: final reduce + BCE + compose ----
    float tp = 0.0f, tl = 0.0f, cls = 0.0f;
    for (int i = threadIdx.x; i < BLOCKS; i += THREADS) {
        tp += coh_load(&partials[2 * i + 0]);
        tl += coh_load(&partials[2 * i + 1]);
    }
    for (int i = threadIdx.x; i < nb; i += THREADS) {
        float x = logit[i];
        float y = yf[i];
        cls += fmaxf(x, 0.0f) - x * y + log1pf(__expf(-fabsf(x)));
    }

    tp  = wave_reduce(tp);
    tl  = wave_reduce(tl);
    cls = wave_reduce(cls);

    __shared__ float fp[4], fl[4], fc[4];
    if (lane == 0) { fp[w] = tp; fl[w] = tl; fc[w] = cls; }
    __syncthreads();
    if (threadIdx.x == 0) {
        float P = fp[0] + fp[1] + fp[2] + fp[3];
        float L = fl[0] + fl[1] + fl[2] + fl[3];
        float C = fc[0] + fc[1] + fc[2] + fc[3];

        float loss_physics = P * inv_ns;
        float loss_M       = L * inv_ns;
        float loss_cls     = C / (float)nb;

        out[0] = loss_M + 0.5f * loss_physics + 0.5f * loss_cls;
        out[1] = loss_M;
        out[2] = loss_physics;
        out[3] = loss_cls;
    }
}

extern "C" void kernel_launch(void* const* d_in, const int* in_sizes, int n_in,
                              void* d_out, int out_size, void* d_ws, size_t ws_size,
                              hipStream_t stream) {
    const float* p_pred   = (const float*)d_in[0];
    const float* p_t_pred = (const float*)d_in[1];
    const float* logit    = (const float*)d_in[2];
    const float* yfault   = (const float*)d_in[3];
    const float* mdot_A   = (const float*)d_in[4];
    const float* tgt_p    = (const float*)d_in[5];
    const float* V        = (const float*)d_in[6];

    int n  = in_sizes[0];       // B*S = 8388608
    int nb = in_sizes[3];       // B = 512
    int n4 = n / 4;

    // ws layout: [0..3] ticket counter, [256..] partials (BLOCKS * 2 floats)
    unsigned* counter  = (unsigned*)d_ws;
    float*    partials = (float*)((char*)d_ws + 256);

    hipMemsetAsync(counter, 0, sizeof(unsigned), stream);

    loss_fused_kernel<<<BLOCKS, THREADS, 0, stream>>>(
        (const float4*)p_pred, (const float4*)p_t_pred,
        (const float4*)mdot_A, (const float4*)tgt_p,
        V, logit, yfault, nb,
        counter, partials,
        (float*)d_out, n4, 1.0f / (float)n);
}